// Round 1
// baseline (609.916 us; speedup 1.0000x reference)
//
#include <hip/hip_runtime.h>
#include <cstdint>
#include <cstddef>

// Problem constants (B=128, S=256, H=128, HEADS=8, STEP=1)
#define BB   128
#define SS   256
#define HH   128
#define NH   8
#define DKK  16

__device__ __forceinline__ float sigmoidf_(float x) { return 1.f / (1.f + expf(-x)); }

// ---------------------------------------------------------------------------
// Generic fp32 tiled GEMM: Out[r,n] = sum_k X[r,k] * B[.,.] + bias[n]
//   BT=true : B is [N,K] row-major  (Out = X @ B^T)
//   BT=false: B is [K,N] row-major  (Out = X @ B)
//   CAT3    : X is the concat [X0 | X1 | X2] along K, each with ld=128
// Tile: 64x64 output per block, BK=16, 256 threads, 4x4 per thread.
// All M,N multiples of 64; K multiple of 16 (true for every call here).
// ---------------------------------------------------------------------------
template <bool BT, bool CAT3>
__global__ __launch_bounds__(256) void gemm_f32(
    const float* __restrict__ X0, const float* __restrict__ X1,
    const float* __restrict__ X2,
    int ldx, long long sX,
    const float* __restrict__ Bm, int ldb, long long sB,
    const float* __restrict__ bias,
    float* __restrict__ Out, int ldo, long long sO,
    int K)
{
    const int bm = blockIdx.x * 64;
    const int bn = blockIdx.y * 64;
    const int bz = blockIdx.z;

    const float* Xb = X0 + (size_t)bz * (size_t)sX;
    const float* Bb = Bm + (size_t)bz * (size_t)sB;
    float*       Ob = Out + (size_t)bz * (size_t)sO;

    __shared__ float Xs[16][65];
    __shared__ float Bs[16][65];

    const int t   = threadIdx.x;
    const int tx  = t & 15;
    const int ty  = t >> 4;
    const int lm  = t >> 2;        // 0..63 (row/col index for x/bt loads)
    const int lk4 = (t & 3) * 4;   // 0,4,8,12
    const int lk16 = t >> 4;       // 0..15 (k row for NN B load)
    const int ln4  = (t & 15) * 4; // 0..60

    float acc[4][4] = {};

    for (int k0 = 0; k0 < K; k0 += 16) {
        // ---- stage X tile (64 rows x 16 k) ----
        const float* xp;
        if (CAT3) {
            const int reg = k0 >> 7;  // k regions of 128: msg_in | msg_out | hidden
            const float* src = (reg == 0) ? X0 : ((reg == 1) ? X1 : X2);
            xp = src + (size_t)(bm + lm) * 128 + ((k0 & 127) + lk4);
        } else {
            xp = Xb + (size_t)(bm + lm) * (size_t)ldx + (k0 + lk4);
        }
        float4 xv = *(const float4*)xp;
        Xs[lk4 + 0][lm] = xv.x;
        Xs[lk4 + 1][lm] = xv.y;
        Xs[lk4 + 2][lm] = xv.z;
        Xs[lk4 + 3][lm] = xv.w;

        // ---- stage B tile ----
        if (BT) {
            const float* bp = Bb + (size_t)(bn + lm) * (size_t)ldb + (k0 + lk4);
            float4 bv = *(const float4*)bp;
            Bs[lk4 + 0][lm] = bv.x;
            Bs[lk4 + 1][lm] = bv.y;
            Bs[lk4 + 2][lm] = bv.z;
            Bs[lk4 + 3][lm] = bv.w;
        } else {
            const float* bp = Bb + (size_t)(k0 + lk16) * (size_t)ldb + (bn + ln4);
            float4 bv = *(const float4*)bp;
            Bs[lk16][ln4 + 0] = bv.x;
            Bs[lk16][ln4 + 1] = bv.y;
            Bs[lk16][ln4 + 2] = bv.z;
            Bs[lk16][ln4 + 3] = bv.w;
        }
        __syncthreads();

        #pragma unroll
        for (int k = 0; k < 16; k++) {
            float a0 = Xs[k][ty * 4 + 0];
            float a1 = Xs[k][ty * 4 + 1];
            float a2 = Xs[k][ty * 4 + 2];
            float a3 = Xs[k][ty * 4 + 3];
            float b0 = Bs[k][tx * 4 + 0];
            float b1 = Bs[k][tx * 4 + 1];
            float b2 = Bs[k][tx * 4 + 2];
            float b3 = Bs[k][tx * 4 + 3];
            acc[0][0] += a0 * b0; acc[0][1] += a0 * b1; acc[0][2] += a0 * b2; acc[0][3] += a0 * b3;
            acc[1][0] += a1 * b0; acc[1][1] += a1 * b1; acc[1][2] += a1 * b2; acc[1][3] += a1 * b3;
            acc[2][0] += a2 * b0; acc[2][1] += a2 * b1; acc[2][2] += a2 * b2; acc[2][3] += a2 * b3;
            acc[3][0] += a3 * b0; acc[3][1] += a3 * b1; acc[3][2] += a3 * b2; acc[3][3] += a3 * b3;
        }
        __syncthreads();
    }

    // ---- epilogue: add bias, float4 stores ----
    const int c0 = bn + tx * 4;
    float4 bv = *(const float4*)&bias[c0];
    #pragma unroll
    for (int i = 0; i < 4; i++) {
        const int r = bm + ty * 4 + i;
        float4 o;
        o.x = acc[i][0] + bv.x;
        o.y = acc[i][1] + bv.y;
        o.z = acc[i][2] + bv.z;
        o.w = acc[i][3] + bv.w;
        *(float4*)&Ob[(size_t)r * (size_t)ldo + c0] = o;
    }
}

// ---------------------------------------------------------------------------
// Assemble W2 [512 x 384] and bias2 [512] for the fused gi+gh GEMM.
//   n in [0,128)  : g_r row  = [w_ih[n][0:256] | w_hh[n][0:128]],  bias b_ih[n]+b_hh[n]
//   n in [128,256): g_i row  = [w_ih[n] | w_hh[n]],                bias b_ih[n]+b_hh[n]
//   n in [256,384): i_n row  = [w_ih[n] | 0],                      bias b_ih[n]
//   n in [384,512): h_n row  = [0 | w_hh[n-128]],                  bias b_hh[n-128]
// ---------------------------------------------------------------------------
__global__ void k_prepw2(const float* __restrict__ w_ih, const float* __restrict__ w_hh,
                         const float* __restrict__ b_ih, const float* __restrict__ b_hh,
                         float* __restrict__ W2, float* __restrict__ bias2)
{
    int idx = blockIdx.x * 256 + threadIdx.x;  // over 512*384 = 196608
    if (idx < 512 * 384) {
        int n = idx / 384;
        int k = idx % 384;
        float v;
        if (n < 256)      v = (k < 256) ? w_ih[n * 256 + k] : w_hh[n * 128 + (k - 256)];
        else if (n < 384) v = (k < 256) ? w_ih[n * 256 + k] : 0.f;
        else              v = (k < 256) ? 0.f : w_hh[(n - 128) * 128 + (k - 256)];
        W2[idx] = v;
    }
    if (idx < 512) {
        int n = idx;
        float bvv;
        if (n < 256)      bvv = b_ih[n] + b_hh[n];
        else if (n < 384) bvv = b_ih[n];
        else              bvv = b_hh[n - 128];
        bias2[n] = bvv;
    }
}

// nvalid[b] = sum(mask[b]); lastidx[b] = (nvalid-1) mod S (mimics jnp -1 wrap)
__global__ void k_mask(const int* __restrict__ mask, int* __restrict__ lastidx,
                       int* __restrict__ nvalid)
{
    int b = threadIdx.x;  // 128 threads, 1 block
    int s = 0;
    for (int j = 0; j < SS; j++) s += mask[b * SS + j];
    nvalid[b] = s;
    lastidx[b] = (s - 1) & (SS - 1);
}

// GRU gates: hnew = h - sigmoid(g_i)*(h - tanh(i_n + sigmoid(g_r)*h_n))
__global__ __launch_bounds__(256) void k_gates(const float* __restrict__ g4,
                                               const float* __restrict__ hidden,
                                               float* __restrict__ hnew)
{
    size_t idx = (size_t)blockIdx.x * 256 + threadIdx.x;  // B*S*H = 4194304
    int c = (int)(idx & 127);
    size_t row = idx >> 7;
    const float* g = g4 + row * 512;
    float gr = g[c];
    float gi = g[128 + c];
    float in_ = g[256 + c];
    float hn = g[384 + c];
    float h = hidden[idx];
    float r = sigmoidf_(gr);
    float ig = sigmoidf_(gi);
    float ng = tanhf(in_ + r * hn);
    hnew[idx] = h - ig * (h - ng);
}

// q0[b] = hnew[b, lastidx[b], :] @ W_q0^T + b_q0
__global__ void k_q0(const float* __restrict__ hnew, const int* __restrict__ lastidx,
                     const float* __restrict__ Wq0, const float* __restrict__ bq0,
                     float* __restrict__ q0buf)
{
    int b = blockIdx.x;
    int n = threadIdx.x;  // 128
    __shared__ float hs[HH];
    const float* hrow = hnew + ((size_t)b * SS + lastidx[b]) * HH;
    hs[n] = hrow[n];
    __syncthreads();
    float s = bq0[n];
    const float* w = Wq0 + (size_t)n * HH;
    #pragma unroll 8
    for (int k = 0; k < HH; k++) s += hs[k] * w[k];
    q0buf[(size_t)b * HH + n] = s;
}

// scores + first softmax: p[b,h,j] = softmax_j( sigmoid( q0[b,h,:] . q1[b,j,h,:] ) )
__global__ __launch_bounds__(256) void k_scores(const float* __restrict__ q0buf,
                                                const float* __restrict__ q1,
                                                float* __restrict__ pbuf)
{
    int h = blockIdx.x;  // 0..7
    int b = blockIdx.y;  // 0..127
    int j = threadIdx.x; // 0..255
    __shared__ float q0s[DKK];
    __shared__ float red[SS];
    if (j < DKK) q0s[j] = q0buf[(size_t)b * HH + h * DKK + j];
    __syncthreads();

    const float4* q1p = (const float4*)(q1 + ((size_t)b * SS + j) * HH + h * DKK);
    float4 v0 = q1p[0], v1 = q1p[1], v2 = q1p[2], v3 = q1p[3];
    float s = 0.f;
    s += q0s[0] * v0.x + q0s[1] * v0.y + q0s[2] * v0.z + q0s[3] * v0.w;
    s += q0s[4] * v1.x + q0s[5] * v1.y + q0s[6] * v1.z + q0s[7] * v1.w;
    s += q0s[8] * v2.x + q0s[9] * v2.y + q0s[10] * v2.z + q0s[11] * v2.w;
    s += q0s[12] * v3.x + q0s[13] * v3.y + q0s[14] * v3.z + q0s[15] * v3.w;
    float a = sigmoidf_(s);

    // block softmax over j (256 threads)
    red[j] = a;
    __syncthreads();
    for (int off = 128; off > 0; off >>= 1) {
        if (j < off) red[j] = fmaxf(red[j], red[j + off]);
        __syncthreads();
    }
    float m = red[0];
    __syncthreads();
    float e = expf(a - m);
    red[j] = e;
    __syncthreads();
    for (int off = 128; off > 0; off >>= 1) {
        if (j < off) red[j] += red[j + off];
        __syncthreads();
    }
    float denom = red[0];
    pbuf[((size_t)b * NH + h) * SS + j] = e / denom;
}

// head-softmax + readout: out[b, h*16+d] = nvalid[b] * sum_j softmax_h(2*p)[h,j] * q2[b,j,h*16+d]
__global__ __launch_bounds__(128) void k_readout(const float* __restrict__ pbuf,
                                                 const float* __restrict__ q2,
                                                 const int* __restrict__ nvalid,
                                                 float* __restrict__ out)
{
    int b = blockIdx.x;
    int t = threadIdx.x;  // 128
    __shared__ float w_s[NH][SS];

    #pragma unroll
    for (int jj = 0; jj < 2; jj++) {
        int j = t + jj * 128;
        float e[NH];
        float den = 0.f;
        #pragma unroll
        for (int h = 0; h < NH; h++) {
            float p = pbuf[((size_t)b * NH + h) * SS + j];
            e[h] = expf(2.f * p);
            den += e[h];
        }
        float inv = 1.f / den;
        #pragma unroll
        for (int h = 0; h < NH; h++) w_s[h][j] = e[h] * inv;
    }
    __syncthreads();

    int h = t >> 4;  // col c=t -> head h = t/16
    float acc = 0.f;
    const float* q2b = q2 + (size_t)b * SS * HH + t;
    for (int j = 0; j < SS; j++) acc += w_s[h][j] * q2b[(size_t)j * HH];
    out[(size_t)b * HH + t] = acc * (float)nvalid[b];
}

// ---------------------------------------------------------------------------
extern "C" void kernel_launch(void* const* d_in, const int* in_sizes, int n_in,
                              void* d_out, int out_size, void* d_ws, size_t ws_size,
                              hipStream_t stream)
{
    const float* A      = (const float*)d_in[0];
    const float* hidden = (const float*)d_in[1];
    const int*   mask   = (const int*)d_in[2];
    const float* w_ih   = (const float*)d_in[3];
    const float* w_hh   = (const float*)d_in[4];
    const float* b_ih   = (const float*)d_in[5];
    const float* b_hh   = (const float*)d_in[6];
    const float* b_iah  = (const float*)d_in[7];
    const float* b_oah  = (const float*)d_in[8];
    const float* W_ein  = (const float*)d_in[9];
    const float* b_ein  = (const float*)d_in[10];
    const float* W_eout = (const float*)d_in[11];
    const float* b_eout = (const float*)d_in[12];
    const float* W_q0   = (const float*)d_in[13];
    const float* b_q0   = (const float*)d_in[14];
    const float* W_q1   = (const float*)d_in[15];
    const float* b_q1   = (const float*)d_in[16];
    const float* W_q2   = (const float*)d_in[17];
    const float* b_q2   = (const float*)d_in[18];
    float* out = (float*)d_out;
    float* ws  = (float*)d_ws;

    // Workspace layout (floats). hnew reuses E_in; q1/q2 reuse msg_in/msg_out.
    const size_t o_Ein    = 0;                       // 4194304  -> later hnew
    const size_t o_Eout   = 4194304;                 // 4194304
    const size_t o_msgin  = 8388608;                 // 4194304  -> later q1
    const size_t o_msgout = 12582912;                // 4194304  -> later q2
    const size_t o_W2     = 16777216;                // 196608
    const size_t o_bias2  = o_W2 + 196608;           // 512
    const size_t o_q0     = o_bias2 + 512;           // 16384
    const size_t o_p      = o_q0 + 16384;            // 262144
    const size_t o_li     = o_p + 262144;            // 128 (int)
    const size_t o_nv     = o_li + 128;              // 128 (int)

    float* E_in   = ws + o_Ein;
    float* E_out  = ws + o_Eout;
    float* msg_in = ws + o_msgin;
    float* msg_out= ws + o_msgout;
    float* W2     = ws + o_W2;
    float* bias2  = ws + o_bias2;
    float* q0buf  = ws + o_q0;
    float* pbuf   = ws + o_p;
    int*   lastidx= (int*)(ws + o_li);
    int*   nvalid = (int*)(ws + o_nv);
    float* hnew   = ws + o_Ein;     // reuse (E dead after msg GEMMs)
    float* q1     = ws + o_msgin;   // reuse (msg dead after g4 GEMM)
    float* q2     = ws + o_msgout;  // reuse
    // g4 gate buffer [B*S, 512] reuses A (exactly same size; A dead after msg)
    float* g4 = (float*)d_in[0];

    const int MM = BB * SS;  // 32768

    // 1. prep
    k_prepw2<<<768, 256, 0, stream>>>(w_ih, w_hh, b_ih, b_hh, W2, bias2);
    k_mask<<<1, 128, 0, stream>>>(mask, lastidx, nvalid);

    // 2. E_in = hidden @ W_ein^T + b_ein ; E_out likewise
    gemm_f32<true, false><<<dim3(MM / 64, HH / 64, 1), 256, 0, stream>>>(
        hidden, nullptr, nullptr, HH, 0, W_ein, HH, 0, b_ein, E_in, HH, 0, HH);
    gemm_f32<true, false><<<dim3(MM / 64, HH / 64, 1), 256, 0, stream>>>(
        hidden, nullptr, nullptr, HH, 0, W_eout, HH, 0, b_eout, E_out, HH, 0, HH);

    // 3. msg_in = A[:,:, :S] @ E_in + b_iah ; msg_out = A[:,:, S:] @ E_out + b_oah
    gemm_f32<false, false><<<dim3(SS / 64, HH / 64, BB), 256, 0, stream>>>(
        A, nullptr, nullptr, 2 * SS, (long long)SS * 2 * SS,
        E_in, HH, (long long)SS * HH, b_iah, msg_in, HH, (long long)SS * HH, SS);
    gemm_f32<false, false><<<dim3(SS / 64, HH / 64, BB), 256, 0, stream>>>(
        A + SS, nullptr, nullptr, 2 * SS, (long long)SS * 2 * SS,
        E_out, HH, (long long)SS * HH, b_oah, msg_out, HH, (long long)SS * HH, SS);

    // 4. g4 = [msg_in|msg_out|hidden] @ W2^T + bias2   (N=512: g_r,g_i,i_n,h_n)
    gemm_f32<true, true><<<dim3(MM / 64, 512 / 64, 1), 256, 0, stream>>>(
        msg_in, msg_out, hidden, 0, 0, W2, 384, 0, bias2, g4, 512, 0, 384);

    // 5. GRU gates -> hnew
    k_gates<<<(MM * HH) / 256, 256, 0, stream>>>(g4, hidden, hnew);

    // 6. q1/q2 projections
    gemm_f32<true, false><<<dim3(MM / 64, HH / 64, 1), 256, 0, stream>>>(
        hnew, nullptr, nullptr, HH, 0, W_q1, HH, 0, b_q1, q1, HH, 0, HH);
    gemm_f32<true, false><<<dim3(MM / 64, HH / 64, 1), 256, 0, stream>>>(
        hnew, nullptr, nullptr, HH, 0, W_q2, HH, 0, b_q2, q2, HH, 0, HH);

    // 7. q0 from last valid row
    k_q0<<<BB, HH, 0, stream>>>(hnew, lastidx, W_q0, b_q0, q0buf);

    // 8. sigmoid scores + softmax over positions
    k_scores<<<dim3(NH, BB), SS, 0, stream>>>(q0buf, q1, pbuf);

    // 9. head softmax + weighted readout
    k_readout<<<BB, HH, 0, stream>>>(pbuf, q2, nvalid, out);
}

// Round 2
// 258.796 us; speedup vs baseline: 2.3567x; 2.3567x over previous
//
#include <hip/hip_runtime.h>
#include <cstdint>
#include <cstddef>

// Problem constants (B=128, S=256, H=128, HEADS=8, STEP=1)
#define BB   128
#define SS   256
#define HH   128
#define NH   8
#define DKK  16

typedef unsigned short u16;
typedef __attribute__((ext_vector_type(8))) short   sh8;    // 8 bf16 = 4 VGPRs (MFMA A/B frag)
typedef __attribute__((ext_vector_type(4))) float   f32x4;  // MFMA C/D frag

__device__ __forceinline__ float sigmoidf_(float x) { return 1.f / (1.f + expf(-x)); }

__device__ __forceinline__ u16 f2bf(float x) {
    union { float f; unsigned int u; } v; v.f = x;
    unsigned int r = (v.u + 0x7fffu + ((v.u >> 16) & 1u)) >> 16;  // RNE (finite inputs)
    return (u16)r;
}
__device__ __forceinline__ float bf2f(u16 u) {
    union { unsigned int u; float f; } v; v.u = ((unsigned int)u) << 16;
    return v.f;
}

// ---------------------------------------------------------------------------
// bf16 MFMA GEMM, 128x128 tile, BK=32, 256 threads = 4 waves, each wave 64x64
// (4x4 grid of 16x16x32 MFMA).  All B operands are B^T layout [N][K] bf16.
// XMODE: 0 = bf16 [M][K] row-major;  1 = fp32 [M][K] (convert while staging);
//        2 = concat of two bf16 sources along K (split at ksplit)
// OMODE: 0 = fp32 row-major;  1 = bf16 row-major;  2 = bf16 TRANSPOSED
//        (Out[col*ldo + row], packed ushort4 per C-quad)
// Batch (grid.z): z -> zb=z>>1, zh=z&1; element offsets = zb*s?b + zh*s?h.
// All dims are exact multiples of tile sizes for every call — no bounds checks.
// ---------------------------------------------------------------------------
#define BKk 32
#define PK  40   // LDS K pitch in halves (32 + 8): conflict-free frag reads

template<int XMODE, int OMODE>
__global__ __launch_bounds__(256) void gemm_mfma(
    const void* __restrict__ Xa, const void* __restrict__ Xc, int ldx, int ldx1, int ksplit,
    long long sXb, long long sXh,
    const u16* __restrict__ Bw, int ldb, long long sBb, long long sBh,
    const float* __restrict__ bias,
    void* __restrict__ Out, long long ldo, long long sOb, long long sOh,
    int K)
{
    __shared__ u16 As[128 * PK];
    __shared__ u16 Bs[128 * PK];

    const int t  = threadIdx.x;
    const int bm = blockIdx.x * 128;
    const int bn = blockIdx.y * 128;
    const long long zb = blockIdx.z >> 1, zh = blockIdx.z & 1;

    const u16* Bp = Bw + zb * sBb + zh * sBh;

    const int wave = t >> 6, lane = t & 63;
    const int wr = (wave >> 1) * 64, wc = (wave & 1) * 64;
    const int fm = lane & 15, fq = lane >> 4;

    f32x4 acc[4][4] = {};

    const int r0  = t >> 2, kk0 = (t & 3) * 8;  // bf16 staging: 8 halves (16B)/chunk, 2 chunks
    const int r1  = t >> 3, kk1 = (t & 7) * 4;  // fp32 staging: 4 floats -> 4 bf16, 4 chunks

    for (int k0 = 0; k0 < K; k0 += BKk) {
        // ---- stage X tile (128 x 32) ----
        if (XMODE == 1) {
            const float* Xf = (const float*)Xa + zb * sXb + zh * sXh;
            #pragma unroll
            for (int c = 0; c < 4; c++) {
                int r = r1 + 32 * c;
                float4 v = *(const float4*)(Xf + (long long)(bm + r) * ldx + k0 + kk1);
                ushort4 w = { f2bf(v.x), f2bf(v.y), f2bf(v.z), f2bf(v.w) };
                *(ushort4*)&As[r * PK + kk1] = w;
            }
        } else {
            #pragma unroll
            for (int c = 0; c < 2; c++) {
                int r = r0 + 64 * c;
                const u16* src;
                if (XMODE == 2 && k0 >= ksplit)
                    src = (const u16*)Xc + (long long)(bm + r) * ldx1 + (k0 - ksplit) + kk0;
                else
                    src = (const u16*)Xa + (long long)(bm + r) * ldx + k0 + kk0;
                uint4 v = *(const uint4*)src;
                *(uint4*)&As[r * PK + kk0] = v;
            }
        }
        // ---- stage B tile (128 x 32), B^T rows ----
        #pragma unroll
        for (int c = 0; c < 2; c++) {
            int r = r0 + 64 * c;
            uint4 v = *(const uint4*)(Bp + (long long)(bn + r) * ldb + k0 + kk0);
            *(uint4*)&Bs[r * PK + kk0] = v;
        }
        __syncthreads();

        sh8 af[4], bfr[4];
        #pragma unroll
        for (int i = 0; i < 4; i++) af[i]  = *(const sh8*)&As[(wr + i * 16 + fm) * PK + fq * 8];
        #pragma unroll
        for (int j = 0; j < 4; j++) bfr[j] = *(const sh8*)&Bs[(wc + j * 16 + fm) * PK + fq * 8];
        #pragma unroll
        for (int i = 0; i < 4; i++)
            #pragma unroll
            for (int j = 0; j < 4; j++)
                acc[i][j] = __builtin_amdgcn_mfma_f32_16x16x32_bf16(af[i], bfr[j], acc[i][j], 0, 0, 0);
        __syncthreads();
    }

    // ---- epilogue: C layout col=lane&15, row=(lane>>4)*4+reg ----
    #pragma unroll
    for (int j = 0; j < 4; j++) {
        const int col = bn + wc + j * 16 + fm;
        const float bj = bias ? bias[col] : 0.f;
        #pragma unroll
        for (int i = 0; i < 4; i++) {
            const int row0 = bm + wr + i * 16 + fq * 4;
            if (OMODE == 0) {
                float* O = (float*)Out + zb * sOb + zh * sOh;
                #pragma unroll
                for (int r = 0; r < 4; r++)
                    O[(long long)(row0 + r) * ldo + col] = acc[i][j][r] + bj;
            } else if (OMODE == 1) {
                u16* O = (u16*)Out + zb * sOb + zh * sOh;
                #pragma unroll
                for (int r = 0; r < 4; r++)
                    O[(long long)(row0 + r) * ldo + col] = f2bf(acc[i][j][r] + bj);
            } else {
                u16* O = (u16*)Out + zb * sOb + zh * sOh;
                ushort4 w = { f2bf(acc[i][j][0] + bj), f2bf(acc[i][j][1] + bj),
                              f2bf(acc[i][j][2] + bj), f2bf(acc[i][j][3] + bj) };
                *(ushort4*)&O[(long long)col * ldo + row0] = w;  // 4 consecutive rows
            }
        }
    }
}

// ---------------------------------------------------------------------------
// Weight prep: all bf16 weight repacks + bias folding.
//   W2bf [512x384]: rows 0:256 = [w_ih | w_hh] (g_r, g_i); 256:384 = [w_ih | 0]
//   (i_n); 384:512 = [0 | w_hh rows 256:384] (h_n).
//   bias2[n] = gate base bias + fold of (b_iah|b_oah) through w_ih (linear).
//   Wcat  [256x128] = [W_ein; W_eout], biascat = [b_ein|b_eout]
//   Wq12  [256x128] = [W_q1; W_q2],   biasq12 = [b_q1|b_q2]
// ---------------------------------------------------------------------------
__global__ __launch_bounds__(256) void k_prepw(
    const float* __restrict__ w_ih, const float* __restrict__ w_hh,
    const float* __restrict__ b_ih, const float* __restrict__ b_hh,
    const float* __restrict__ b_iah, const float* __restrict__ b_oah,
    const float* __restrict__ W_ein, const float* __restrict__ b_ein,
    const float* __restrict__ W_eout, const float* __restrict__ b_eout,
    const float* __restrict__ W_q1, const float* __restrict__ b_q1,
    const float* __restrict__ W_q2, const float* __restrict__ b_q2,
    u16* __restrict__ W2bf, float* __restrict__ bias2,
    u16* __restrict__ Wcat, float* __restrict__ biascat,
    u16* __restrict__ Wq12, float* __restrict__ biasq12)
{
    int idx = blockIdx.x * 256 + threadIdx.x;  // grid covers 196608
    if (idx < 512 * 384) {
        int n = idx / 384, kk = idx % 384;
        float v;
        if (n < 384) v = (kk < 256) ? w_ih[n * 256 + kk]
                                    : (n < 256 ? w_hh[n * 128 + kk - 256] : 0.f);
        else         v = (kk < 256) ? 0.f : w_hh[(n - 128) * 128 + kk - 256];
        W2bf[idx] = f2bf(v);
    }
    if (idx < 256 * 128) {
        int n = idx >> 7, k = idx & 127;
        Wcat[idx] = f2bf(n < 128 ? W_ein[n * 128 + k] : W_eout[(n - 128) * 128 + k]);
        Wq12[idx] = f2bf(n < 128 ? W_q1[n * 128 + k]  : W_q2[(n - 128) * 128 + k]);
    }
    if (idx < 512) {
        int n = idx;
        float s;
        if (n < 256)      s = b_ih[n] + b_hh[n];
        else if (n < 384) s = b_ih[n];
        else              s = b_hh[n - 128];
        if (n < 384) {
            for (int k = 0; k < 128; k++)
                s += w_ih[n * 256 + k] * b_iah[k] + w_ih[n * 256 + 128 + k] * b_oah[k];
        }
        bias2[n] = s;
    }
    if (idx < 256) {
        biascat[idx] = idx < 128 ? b_ein[idx] : b_eout[idx - 128];
        biasq12[idx] = idx < 128 ? b_q1[idx]  : b_q2[idx - 128];
    }
}

// fp32 -> bf16 cast, 4 elems/thread
__global__ __launch_bounds__(256) void k_cast4(const float* __restrict__ in,
                                               u16* __restrict__ outp, int n4)
{
    int i = blockIdx.x * 256 + threadIdx.x;
    if (i < n4) {
        float4 v = ((const float4*)in)[i];
        ushort4 w = { f2bf(v.x), f2bf(v.y), f2bf(v.z), f2bf(v.w) };
        ((ushort4*)outp)[i] = w;
    }
}

// nvalid[b] = sum(mask[b]); lastidx[b] = (nvalid-1) mod S
__global__ void k_mask(const int* __restrict__ mask, int* __restrict__ lastidx,
                       int* __restrict__ nvalid)
{
    int b = threadIdx.x;  // 128 threads, 1 block
    int s = 0;
    for (int j = 0; j < SS; j++) s += mask[b * SS + j];
    nvalid[b] = s;
    lastidx[b] = (s - 1) & (SS - 1);
}

// GRU gates: hnew = h - sigmoid(g_i)*(h - tanh(i_n + sigmoid(g_r)*h_n)); bf16 out
__global__ __launch_bounds__(256) void k_gates(const float* __restrict__ g4,
                                               const float* __restrict__ hidden,
                                               u16* __restrict__ hnew_bf)
{
    size_t idx = (size_t)blockIdx.x * 256 + threadIdx.x;  // B*S*H
    int c = (int)(idx & 127);
    size_t row = idx >> 7;
    const float* g = g4 + row * 512;
    float gr  = g[c];
    float gi  = g[128 + c];
    float in_ = g[256 + c];
    float hn  = g[384 + c];
    float h = hidden[idx];
    float r  = sigmoidf_(gr);
    float ig = sigmoidf_(gi);
    float ng = tanhf(in_ + r * hn);
    hnew_bf[idx] = f2bf(h - ig * (h - ng));
}

// q0[b] = hnew[b, lastidx[b], :] @ W_q0^T + b_q0
__global__ void k_q0(const u16* __restrict__ hnew_bf, const int* __restrict__ lastidx,
                     const float* __restrict__ Wq0, const float* __restrict__ bq0,
                     float* __restrict__ q0buf)
{
    int b = blockIdx.x;
    int n = threadIdx.x;  // 128
    __shared__ float hs[HH];
    const u16* hrow = hnew_bf + ((size_t)b * SS + lastidx[b]) * HH;
    hs[n] = bf2f(hrow[n]);
    __syncthreads();
    float s = bq0[n];
    const float* w = Wq0 + (size_t)n * HH;
    #pragma unroll 8
    for (int k = 0; k < HH; k++) s += hs[k] * w[k];
    q0buf[(size_t)b * HH + n] = s;
}

// scores + first softmax over positions: q1 lives in q12 cols 0:128 (ld 256)
__global__ __launch_bounds__(256) void k_scores(const float* __restrict__ q0buf,
                                                const float* __restrict__ q12,
                                                float* __restrict__ pbuf)
{
    int h = blockIdx.x;  // 0..7
    int b = blockIdx.y;  // 0..127
    int j = threadIdx.x; // 0..255
    __shared__ float q0s[DKK];
    __shared__ float red[SS];
    if (j < DKK) q0s[j] = q0buf[(size_t)b * HH + h * DKK + j];
    __syncthreads();

    const float4* q1p = (const float4*)(q12 + ((size_t)b * SS + j) * 256 + h * DKK);
    float4 v0 = q1p[0], v1 = q1p[1], v2 = q1p[2], v3 = q1p[3];
    float s = 0.f;
    s += q0s[0] * v0.x + q0s[1] * v0.y + q0s[2] * v0.z + q0s[3] * v0.w;
    s += q0s[4] * v1.x + q0s[5] * v1.y + q0s[6] * v1.z + q0s[7] * v1.w;
    s += q0s[8] * v2.x + q0s[9] * v2.y + q0s[10] * v2.z + q0s[11] * v2.w;
    s += q0s[12] * v3.x + q0s[13] * v3.y + q0s[14] * v3.z + q0s[15] * v3.w;
    float a = sigmoidf_(s);

    red[j] = a;
    __syncthreads();
    for (int off = 128; off > 0; off >>= 1) {
        if (j < off) red[j] = fmaxf(red[j], red[j + off]);
        __syncthreads();
    }
    float m = red[0];
    __syncthreads();
    float e = expf(a - m);
    red[j] = e;
    __syncthreads();
    for (int off = 128; off > 0; off >>= 1) {
        if (j < off) red[j] += red[j + off];
        __syncthreads();
    }
    float denom = red[0];
    pbuf[((size_t)b * NH + h) * SS + j] = e / denom;
}

// head softmax + readout: q2 lives in q12 cols 128:256 (ld 256)
__global__ __launch_bounds__(128) void k_readout(const float* __restrict__ pbuf,
                                                 const float* __restrict__ q12,
                                                 const int* __restrict__ nvalid,
                                                 float* __restrict__ out)
{
    int b = blockIdx.x;
    int t = threadIdx.x;  // 128
    __shared__ float w_s[NH][SS];

    #pragma unroll
    for (int jj = 0; jj < 2; jj++) {
        int j = t + jj * 128;
        float e[NH];
        float den = 0.f;
        #pragma unroll
        for (int h = 0; h < NH; h++) {
            float p = pbuf[((size_t)b * NH + h) * SS + j];
            e[h] = expf(2.f * p);
            den += e[h];
        }
        float inv = 1.f / den;
        #pragma unroll
        for (int h = 0; h < NH; h++) w_s[h][j] = e[h] * inv;
    }
    __syncthreads();

    int h = t >> 4;
    float acc = 0.f;
    const float* q2b = q12 + (size_t)b * SS * 256 + 128 + t;
    for (int j = 0; j < SS; j++) acc += w_s[h][j] * q2b[(size_t)j * 256];
    out[(size_t)b * HH + t] = acc * (float)nvalid[b];
}

// ---------------------------------------------------------------------------
extern "C" void kernel_launch(void* const* d_in, const int* in_sizes, int n_in,
                              void* d_out, int out_size, void* d_ws, size_t ws_size,
                              hipStream_t stream)
{
    const float* A      = (const float*)d_in[0];
    const float* hidden = (const float*)d_in[1];
    const int*   mask   = (const int*)d_in[2];
    const float* w_ih   = (const float*)d_in[3];
    const float* w_hh   = (const float*)d_in[4];
    const float* b_ih   = (const float*)d_in[5];
    const float* b_hh   = (const float*)d_in[6];
    const float* b_iah  = (const float*)d_in[7];
    const float* b_oah  = (const float*)d_in[8];
    const float* W_ein  = (const float*)d_in[9];
    const float* b_ein  = (const float*)d_in[10];
    const float* W_eout = (const float*)d_in[11];
    const float* b_eout = (const float*)d_in[12];
    const float* W_q0   = (const float*)d_in[13];
    const float* b_q0   = (const float*)d_in[14];
    const float* W_q1   = (const float*)d_in[15];
    const float* b_q1   = (const float*)d_in[16];
    const float* W_q2   = (const float*)d_in[17];
    const float* b_q2   = (const float*)d_in[18];
    float* out = (float*)d_out;
    char* ws = (char*)d_ws;

    // --- workspace layout (bytes) ---
    // [0, 33.5MB): Et (16.7MB) + Mbuf (16.7MB); later aliased by q12 (fp32, 33.5MB)
    u16*   Et      = (u16*)(ws + 0);             // [256][32768] bf16 (E transposed)
    u16*   Mbuf    = (u16*)(ws + 16777216);      // [32768][256] bf16 (msg_in|msg_out)
    float* q12     = (float*)(ws + 0);           // [32768][256] fp32 (q1|q2) — aliases Et+Mbuf
    u16*   h_bf    = (u16*)(ws + 33554432);      // [32768][128] bf16
    u16*   hnew_bf = (u16*)(ws + 41943040);      // [32768][128] bf16
    u16*   W2bf    = (u16*)(ws + 50331648);      // [512][384]
    u16*   Wcat    = (u16*)(ws + 50724864);      // [256][128]
    u16*   Wq12    = (u16*)(ws + 50790400);      // [256][128]
    float* bias2   = (float*)(ws + 50855936);    // [512]
    float* biascat = (float*)(ws + 50857984);    // [256]
    float* biasq12 = (float*)(ws + 50859008);    // [256]
    float* q0buf   = (float*)(ws + 50860032);    // [128][128]
    float* pbuf    = (float*)(ws + 50925568);    // [128][8][256]
    int*   lastidx = (int*)(ws + 51974144);      // [128]
    int*   nvalid  = (int*)(ws + 51974656);      // [128]
    // g4 gate buffer [32768][512] fp32 reuses A (same size; A dead after msg GEMM)
    float* g4 = (float*)d_in[0];

    // 1. prep
    k_prepw<<<768, 256, 0, stream>>>(w_ih, w_hh, b_ih, b_hh, b_iah, b_oah,
                                     W_ein, b_ein, W_eout, b_eout,
                                     W_q1, b_q1, W_q2, b_q2,
                                     W2bf, bias2, Wcat, biascat, Wq12, biasq12);
    k_mask<<<1, 128, 0, stream>>>(mask, lastidx, nvalid);
    k_cast4<<<4096, 256, 0, stream>>>(hidden, h_bf, 1048576);

    // 2. E = h @ Wcat^T + biascat, stored TRANSPOSED: Et[c][r], ldo=32768
    gemm_mfma<0, 2><<<dim3(256, 2, 1), 256, 0, stream>>>(
        h_bf, nullptr, 128, 0, 0, 0, 0,
        Wcat, 128, 0, 0, biascat,
        Et, 32768, 0, 0, 128);

    // 3. msg: per (b,half): A-half[b] (fp32, ld 512) @ Et-slice^T -> Mbuf bf16
    gemm_mfma<1, 1><<<dim3(2, 1, 256), 256, 0, stream>>>(
        A, nullptr, 512, 0, 0, 131072LL, 256LL,
        Et, 32768, 256LL, 128LL * 32768LL, nullptr,
        Mbuf, 256, 65536LL, 128LL, 256);

    // 4. g4 = [Mbuf | h_bf] @ W2bf^T + bias2 (fp32 out, reuses A's memory)
    gemm_mfma<2, 0><<<dim3(256, 4, 1), 256, 0, stream>>>(
        Mbuf, h_bf, 256, 128, 256, 0, 0,
        W2bf, 384, 0, 0, bias2,
        g4, 512, 0, 0, 384);

    // 5. GRU gates -> hnew (bf16)
    k_gates<<<16384, 256, 0, stream>>>(g4, hidden, hnew_bf);

    // 6. q12 = hnew @ [W_q1;W_q2]^T + bias (fp32 out, aliases Et+Mbuf region)
    gemm_mfma<0, 0><<<dim3(256, 2, 1), 256, 0, stream>>>(
        hnew_bf, nullptr, 128, 0, 0, 0, 0,
        Wq12, 128, 0, 0, biasq12,
        q12, 256, 0, 0, 128);

    // 7-9. attention tail
    k_q0<<<BB, HH, 0, stream>>>(hnew_bf, lastidx, W_q0, b_q0, q0buf);
    k_scores<<<dim3(NH, BB), SS, 0, stream>>>(q0buf, q12, pbuf);
    k_readout<<<BB, HH, 0, stream>>>(pbuf, q12, nvalid, out);
}